// Round 1
// 188.650 us; speedup vs baseline: 1.0013x; 1.0013x over previous
//
#include <hip/hip_runtime.h>

// Pairlist: 2000 molecules x 64 atoms, ordered intra-molecule pairs.
// Out (flat f32): i[P], j[P], d[P], r_ij[P*3]; P = 8,064,000. Write-bound.
// R3: single-phase streaming. The R2 kernel staged r_ij through a 13KB LDS
// transpose with a second __syncthreads between the two store bursts; that
// barrier + LDS round-trip sat on the critical path of the store stream.
// Here the r-stream float4s are produced directly: each thread owns 3
// CONTIGUOUS float4s of the r-stream and recomputes the two pair vectors
// that straddle each one (VALUBusy was ~5% -> recompute is free). One
// barrier total, 1.5 KB LDS, every store full-line lane-contiguous.

#define N_MOL   2000
#define MOL_A   64
#define PPM     (MOL_A * (MOL_A - 1))    // 4032 pairs / molecule
#define P_TOTAL (N_MOL * PPM)            // 8,064,000
#define BLOCK   256
#define PPB     1024                     // pairs per block (4 per thread)

__global__ __launch_bounds__(BLOCK) void Pairlist_54932631716418_kernel(
    const float* __restrict__ pos, float* __restrict__ out) {
  __shared__ float posb[2 * MOL_A * 3];  // 2 molecules * 192 words = 1.5 KB

  const int t  = threadIdx.x;
  const int P0 = blockIdx.x * PPB;
  const int mf = P0 / PPM;               // first molecule this block touches

  // ---- stage up to 2 molecules of positions as float4 (clamped: the last
  //      block only has molecule 1999; clamp keeps loads in-bounds, the
  //      garbage second half is never read there) ----
  if (t < 96) {
    int idx = mf * 48 + t;               // 96 float4 = 384 words
    if (idx > N_MOL * 48 - 1) idx = N_MOL * 48 - 1;
    ((float4*)posb)[t] = ((const float4*)pos)[idx];
  }
  __syncthreads();

  const int rpBase = P0 - mf * PPM;      // block-local pair -> mol-relative

  // ---- phase 1: 4 consecutive pairs -> i, j, d (one float4 store each).
  //      4032 % 4 == 0 and rpBase % 4 == 0, so a 4-group never straddles. ----
  {
    int rp = rpBase + 4 * t;
    int molOff = 0, base = mf * MOL_A;
    if (rp >= PPM) { rp -= PPM; molOff = MOL_A * 3; base += MOL_A; }
    float fi[4], fj[4], fd[4];
#pragma unroll
    for (int s = 0; s < 4; ++s) {
      const int r = rp + s;
      const int i = r / 63;              // magic-mul
      const int k = r - 63 * i;
      const int j = k + (k >= i ? 1 : 0);
      const float rx = posb[molOff + 3 * j + 0] - posb[molOff + 3 * i + 0];
      const float ry = posb[molOff + 3 * j + 1] - posb[molOff + 3 * i + 1];
      const float rz = posb[molOff + 3 * j + 2] - posb[molOff + 3 * i + 2];
      fi[s] = (float)(base + i);
      fj[s] = (float)(base + j);
      fd[s] = sqrtf(rx * rx + ry * ry + rz * rz);
    }
    const int p0 = P0 + 4 * t;           // 16B-aligned; wave covers 1KB/stream
    *(float4*)(out + p0)               = make_float4(fi[0], fi[1], fi[2], fi[3]);
    *(float4*)(out + P_TOTAL + p0)     = make_float4(fj[0], fj[1], fj[2], fj[3]);
    *(float4*)(out + 2 * P_TOTAL + p0) = make_float4(fd[0], fd[1], fd[2], fd[3]);
  }

  // ---- phase 2: r-stream, contiguous float4s, recomputed from posb.
  //      Block's r-words are [3*P0, 3*P0 + 3072) = 768 float4, 3 per thread.
  //      float4 g covers words F0..F0+3 (F0 = 4g), i.e. pairs pA = F0/3 and
  //      pA+1, component phase b = F0 % 3. ----
  float* outr = out + 3 * (size_t)P_TOTAL + 3 * (size_t)P0;
#pragma unroll
  for (int s = 0; s < 3; ++s) {
    const int g  = t + s * BLOCK;        // [0, 768)
    const int F0 = 4 * g;                // [0, 3072)
    const int pA = F0 / 3;               // magic-mul; pA <= 1022
    const int b  = F0 - 3 * pA;

    // pair A (each pair resolves its own molecule: straddle-safe)
    int rp = rpBase + pA, off = 0;
    if (rp >= PPM) { rp -= PPM; off = MOL_A * 3; }
    int i = rp / 63;
    int k = rp - 63 * i;
    int j = k + (k >= i ? 1 : 0);
    const float rAx = posb[off + 3 * j + 0] - posb[off + 3 * i + 0];
    const float rAy = posb[off + 3 * j + 1] - posb[off + 3 * i + 1];
    const float rAz = posb[off + 3 * j + 2] - posb[off + 3 * i + 2];

    // pair B = pA + 1 (pB <= 1023, always inside this block's range)
    rp = rpBase + pA + 1; off = 0;
    if (rp >= PPM) { rp -= PPM; off = MOL_A * 3; }
    i = rp / 63;
    k = rp - 63 * i;
    j = k + (k >= i ? 1 : 0);
    const float rBx = posb[off + 3 * j + 0] - posb[off + 3 * i + 0];
    const float rBy = posb[off + 3 * j + 1] - posb[off + 3 * i + 1];
    const float rBz = posb[off + 3 * j + 2] - posb[off + 3 * i + 2];

    // branchless component select by phase b (word W=F0+w: pair (F0+w)/3,
    // component (F0+w)%3)
    float4 v;
    v.x = (b == 0) ? rAx : ((b == 1) ? rAy : rAz);
    v.y = (b == 0) ? rAy : ((b == 1) ? rAz : rBx);
    v.z = (b == 0) ? rAz : ((b == 1) ? rBx : rBy);
    v.w = (b == 0) ? rBx : ((b == 1) ? rBy : rBz);
    *(float4*)(outr + F0) = v;           // lane-contiguous 1KB per wave-store
  }
}

extern "C" void kernel_launch(void* const* d_in, const int* in_sizes, int n_in,
                              void* d_out, int out_size, void* d_ws, size_t ws_size,
                              hipStream_t stream) {
  const float* pos = (const float*)d_in[0];   // positions [128000, 3] f32
  float* out = (float*)d_out;
  const int blocks = P_TOTAL / PPB;           // 7875 exact
  Pairlist_54932631716418_kernel<<<blocks, BLOCK, 0, stream>>>(pos, out);
}